// Round 12
// baseline (224.180 us; speedup 1.0000x reference)
//
#include <hip/hip_runtime.h>
#include <hip/hip_bf16.h>

#define B_ 4
#define N_ 1024
#define C_ 1024
#define H_ 16
#define D_ 64

typedef __attribute__((ext_vector_type(8))) short bf16x8;
typedef __attribute__((ext_vector_type(4))) float f32x4;

__device__ __forceinline__ void gld_lds16(const void* g, void* l) {
    __builtin_amdgcn_global_load_lds(
        (const __attribute__((address_space(1))) void*)g,
        (__attribute__((address_space(3))) void*)l, 16, 0, 0);
}

// ---------------------------------------------------------------- fp32 -> bf16
__global__ __launch_bounds__(256) void f2b_kernel(const float* __restrict__ s,
                                                  __hip_bfloat16* __restrict__ d,
                                                  int n) {
    int i = (blockIdx.x * 256 + threadIdx.x) * 4;
    if (i < n) {
        float4 v = *(const float4*)&s[i];
        d[i + 0] = __float2bfloat16(v.x);
        d[i + 1] = __float2bfloat16(v.y);
        d[i + 2] = __float2bfloat16(v.z);
        d[i + 3] = __float2bfloat16(v.w);
    }
}

// 4 weight matrices in one dispatch (blockIdx.y selects)
__global__ __launch_bounds__(256) void f2b4_kernel(const float* __restrict__ w0,
                                                   const float* __restrict__ w1,
                                                   const float* __restrict__ w2,
                                                   const float* __restrict__ w3,
                                                   __hip_bfloat16* __restrict__ d0,
                                                   __hip_bfloat16* __restrict__ d1,
                                                   __hip_bfloat16* __restrict__ d2,
                                                   __hip_bfloat16* __restrict__ d3) {
    int sel = blockIdx.y;
    const float* s = sel == 0 ? w0 : sel == 1 ? w1 : sel == 2 ? w2 : w3;
    __hip_bfloat16* d = sel == 0 ? d0 : sel == 1 ? d1 : sel == 2 ? d2 : d3;
    int i = (blockIdx.x * 256 + threadIdx.x) * 4;
    float4 v = *(const float4*)&s[i];
    d[i + 0] = __float2bfloat16(v.x);
    d[i + 1] = __float2bfloat16(v.y);
    d[i + 2] = __float2bfloat16(v.z);
    d[i + 3] = __float2bfloat16(v.w);
}

// ---------------------------------------------------------------- fused QKV GEMM
// ROUND-2-PROVEN version: 128x128 tile, BK=32, linear LDS.
__global__ __launch_bounds__(256) void gemm_qkv(const __hip_bfloat16* __restrict__ A,
                                                const __hip_bfloat16* __restrict__ wq,
                                                const __hip_bfloat16* __restrict__ wk,
                                                const __hip_bfloat16* __restrict__ wv,
                                                const float* __restrict__ bq,
                                                const float* __restrict__ bk,
                                                const float* __restrict__ bv,
                                                __hip_bfloat16* __restrict__ qo,
                                                __hip_bfloat16* __restrict__ ko,
                                                __hip_bfloat16* __restrict__ vto) {
    __shared__ __hip_bfloat16 Al[128 * 32];
    __shared__ __hip_bfloat16 Bl[128 * 32];
    const int sel = blockIdx.x >> 3;
    const __hip_bfloat16* Bw = sel == 0 ? wq : sel == 1 ? wk : wv;
    const float* bias = sel == 0 ? bq : sel == 1 ? bk : bv;
    const int t = threadIdx.x, w = t >> 6, l = t & 63;
    const int wr = w >> 1, wc = w & 1, lr = l & 15, lg = l >> 4;
    const int m0 = blockIdx.y * 128, n0 = (blockIdx.x & 7) * 128;
    const int K = C_;

    f32x4 acc[4][4] = {};

    for (int k0 = 0; k0 < K; k0 += 32) {
#pragma unroll
        for (int it = 0; it < 2; ++it) {
            int i = t + it * 256;
            int r = i >> 2, c8 = (i & 3) * 8;
            gld_lds16(A + (size_t)(m0 + r) * K + k0 + c8, &Al[i * 8]);
            gld_lds16(Bw + (size_t)(n0 + r) * K + k0 + c8, &Bl[i * 8]);
        }
        __syncthreads();
        bf16x8 af[4], bfr[4];
#pragma unroll
        for (int mi = 0; mi < 4; ++mi)
            af[mi] = *(const bf16x8*)&Al[(wr * 64 + mi * 16 + lr) * 32 + lg * 8];
#pragma unroll
        for (int ni = 0; ni < 4; ++ni)
            bfr[ni] = *(const bf16x8*)&Bl[(wc * 64 + ni * 16 + lr) * 32 + lg * 8];
#pragma unroll
        for (int mi = 0; mi < 4; ++mi)
#pragma unroll
            for (int ni = 0; ni < 4; ++ni)
                acc[mi][ni] = __builtin_amdgcn_mfma_f32_16x16x32_bf16(
                    af[mi], bfr[ni], acc[mi][ni], 0, 0, 0);
        __syncthreads();
    }

#pragma unroll
    for (int mi = 0; mi < 4; ++mi) {
#pragma unroll
        for (int ni = 0; ni < 4; ++ni) {
            int col = n0 + wc * 64 + ni * 16 + lr;
            float bb = bias[col];
#pragma unroll
            for (int j = 0; j < 4; ++j) {
                int row = m0 + wr * 64 + mi * 16 + lg * 4 + j;
                float v = acc[mi][ni][j] + bb;
                int bb_ = row >> 10, nn = row & 1023;
                int hh = col >> 6, dd = col & 63;
                if (sel == 0) {
                    qo[(((size_t)bb_ * H_ + hh) * N_ + nn) * D_ + dd] =
                        __float2bfloat16(v * 0.125f);
                } else if (sel == 1) {
                    ko[(((size_t)bb_ * H_ + hh) * N_ + nn) * D_ + dd] =
                        __float2bfloat16(v);
                } else {
                    vto[(((size_t)bb_ * H_ + hh) * D_ + dd) * N_ + nn] =
                        __float2bfloat16(v);
                }
            }
        }
    }
}

// ---------------------------------------------------------------- output proj GEMM
__global__ __launch_bounds__(256) void gemm_out(const __hip_bfloat16* __restrict__ A,
                                                const __hip_bfloat16* __restrict__ Bw,
                                                const float* __restrict__ bias,
                                                float* __restrict__ out) {
    __shared__ __hip_bfloat16 Al[128 * 32];
    __shared__ __hip_bfloat16 Bl[128 * 32];
    const int t = threadIdx.x, w = t >> 6, l = t & 63;
    const int wr = w >> 1, wc = w & 1, lr = l & 15, lg = l >> 4;
    const int m0 = blockIdx.y * 128, n0 = blockIdx.x * 128;
    const int K = C_;

    f32x4 acc[4][4] = {};

    for (int k0 = 0; k0 < K; k0 += 32) {
#pragma unroll
        for (int it = 0; it < 2; ++it) {
            int i = t + it * 256;
            int r = i >> 2, c8 = (i & 3) * 8;
            gld_lds16(A + (size_t)(m0 + r) * K + k0 + c8, &Al[i * 8]);
            gld_lds16(Bw + (size_t)(n0 + r) * K + k0 + c8, &Bl[i * 8]);
        }
        __syncthreads();
        bf16x8 af[4], bfr[4];
#pragma unroll
        for (int mi = 0; mi < 4; ++mi)
            af[mi] = *(const bf16x8*)&Al[(wr * 64 + mi * 16 + lr) * 32 + lg * 8];
#pragma unroll
        for (int ni = 0; ni < 4; ++ni)
            bfr[ni] = *(const bf16x8*)&Bl[(wc * 64 + ni * 16 + lr) * 32 + lg * 8];
#pragma unroll
        for (int mi = 0; mi < 4; ++mi)
#pragma unroll
            for (int ni = 0; ni < 4; ++ni)
                acc[mi][ni] = __builtin_amdgcn_mfma_f32_16x16x32_bf16(
                    af[mi], bfr[ni], acc[mi][ni], 0, 0, 0);
        __syncthreads();
    }

#pragma unroll
    for (int mi = 0; mi < 4; ++mi)
#pragma unroll
        for (int ni = 0; ni < 4; ++ni) {
            int col = n0 + wc * 64 + ni * 16 + lr;
            float bb = bias[col];
#pragma unroll
            for (int j = 0; j < 4; ++j) {
                int row = m0 + wr * 64 + mi * 16 + lg * 4 + j;
                out[(size_t)row * C_ + col] = acc[mi][ni][j] + bb;
            }
        }
}

// ---------------------------------------------------------------- attention
// BARRIER-FREE per-wave pipeline (MODE2 evidence: barrier gang costs ~2x).
// K/V fragments in REGISTERS (no LDS staging -> no cross-wave visibility
// needed -> zero s_barrier in loop). Each load class is issued right after
// its consumer cluster -> ~3/4 iteration of latency slack, ~20 loads in
// flight per wave. Register loads are self-synchronizing: the compiler
// emits exact counted vmcnt before first use. sched_barrier(0) only pins
// cluster order. P relayout via wave-private LDS (lgkmcnt, no barrier).
__global__ __launch_bounds__(256, 3) void attn_kernel(const __hip_bfloat16* __restrict__ q,
                                                      const __hip_bfloat16* __restrict__ k,
                                                      const __hip_bfloat16* __restrict__ vt,
                                                      const float* __restrict__ bias,
                                                      const int* __restrict__ mask,
                                                      __hip_bfloat16* __restrict__ ao) {
    const int orig = blockIdx.x;
    const int wg = (orig & 7) * 128 + (orig >> 3);  // bijective XCD swizzle (1024 % 8 == 0)
    const int qt = wg & 15, h = (wg >> 4) & 15, b = wg >> 8;
    const int t = threadIdx.x, w = t >> 6, l = t & 63;
    const int lr = l & 15, lg = l >> 4;

    __shared__ float Pen[1024];               // mask penalties, 4 KB
    __shared__ __hip_bfloat16 Pl[4][16][72];  // per-wave P buffer, 9.2 KB

    const size_t bh = (size_t)b * H_ + h;
    const int qr0 = qt * 64;
    const int myrow = qr0 + w * 16 + lr;
    const int orow_base = qr0 + w * 16 + lg * 4;

    // ---- mask -> additive penalties in LDS (one-time; only barrier in kernel)
    {
        int4 mi = *(const int4*)&mask[b * N_ + t * 4];
        float4 p;
        p.x = mi.x ? 0.f : -1e30f;
        p.y = mi.y ? 0.f : -1e30f;
        p.z = mi.z ? 0.f : -1e30f;
        p.w = mi.w ? 0.f : -1e30f;
        *(float4*)&Pen[t * 4] = p;
    }
    __syncthreads();

    // ---- Q fragment (B-operand of swapped QK^T), held all loop
    bf16x8 qf[2];
#pragma unroll
    for (int half = 0; half < 2; ++half)
        qf[half] = *(const bf16x8*)&q[(bh * N_ + myrow) * D_ + half * 32 + lg * 8];

    const float* brow = bias + ((size_t)bh * N_ + myrow) * N_;
    const __hip_bfloat16* kb0 = k + (bh * N_ + lr) * D_ + lg * 8;   // + nkb*16*D + kt*64*D + half*32
    const __hip_bfloat16* vb0 = vt + (bh * D_ + lr) * N_ + lg * 8;  // + db*16*N + kt*64 + mh*32

    f32x4 acc[4] = {};
    float m_ = -3e38f, l_ = 0.f;

    // ---- prologue: K(0), V(0), bias(0) into registers
    bf16x8 kf[4][2], vf[4][2];
    f32x4 bcur[4];
#pragma unroll
    for (int nkb = 0; nkb < 4; ++nkb)
#pragma unroll
        for (int half = 0; half < 2; ++half)
            kf[nkb][half] = *(const bf16x8*)&kb0[(nkb * 16) * D_ + half * 32];
#pragma unroll
    for (int db = 0; db < 4; ++db)
#pragma unroll
        for (int mh = 0; mh < 2; ++mh)
            vf[db][mh] = *(const bf16x8*)&vb0[(db * 16) * (size_t)N_ + mh * 32];
#pragma unroll
    for (int nkb = 0; nkb < 4; ++nkb)
        bcur[nkb] = *(const f32x4*)&brow[nkb * 16 + lg * 4];

    for (int kt = 0; kt < 16; ++kt) {
        const int ktn = kt < 15 ? kt + 1 : 15;

        // c1: QK^T (consumes kf(kt); compiler inserts the counted vmcnt here)
        float s[4][4];
        __builtin_amdgcn_s_setprio(1);
#pragma unroll
        for (int nkb = 0; nkb < 4; ++nkb) {
            f32x4 a = {};
#pragma unroll
            for (int half = 0; half < 2; ++half)
                a = __builtin_amdgcn_mfma_f32_16x16x32_bf16(kf[nkb][half], qf[half],
                                                            a, 0, 0, 0);
#pragma unroll
            for (int j = 0; j < 4; ++j) s[nkb][j] = a[j];
        }
        __builtin_amdgcn_s_setprio(0);
        __builtin_amdgcn_sched_barrier(0);

        // c2: issue K(kt+1) (refills kf; ~full iteration until next use)
#pragma unroll
        for (int nkb = 0; nkb < 4; ++nkb)
#pragma unroll
            for (int half = 0; half < 2; ++half)
                kf[nkb][half] = *(const bf16x8*)
                    &kb0[((size_t)ktn * 64 + nkb * 16) * D_ + half * 32];
        __builtin_amdgcn_sched_barrier(0);

        // c3: bias + pen, online softmax (consumes bcur(kt))
#pragma unroll
        for (int nkb = 0; nkb < 4; ++nkb) {
            f32x4 pen = *(const f32x4*)&Pen[kt * 64 + nkb * 16 + lg * 4];
#pragma unroll
            for (int j = 0; j < 4; ++j) s[nkb][j] += bcur[nkb][j] + pen[j];
        }
        float tm = s[0][0];
#pragma unroll
        for (int nkb = 0; nkb < 4; ++nkb)
#pragma unroll
            for (int j = 0; j < 4; ++j) tm = fmaxf(tm, s[nkb][j]);
        tm = fmaxf(tm, __shfl_xor(tm, 16));
        tm = fmaxf(tm, __shfl_xor(tm, 32));
        const float mn = fmaxf(m_, tm);
        const float al = __expf(m_ - mn);
        m_ = mn;
        float ts = 0.f;
#pragma unroll
        for (int nkb = 0; nkb < 4; ++nkb)
#pragma unroll
            for (int j = 0; j < 4; ++j) {
                float p = __expf(s[nkb][j] - mn);
                s[nkb][j] = p;
                ts += p;
            }
        ts += __shfl_xor(ts, 16);
        ts += __shfl_xor(ts, 32);
        l_ = l_ * al + ts;
        __builtin_amdgcn_sched_barrier(0);

        // c4: issue bias(kt+1)
#pragma unroll
        for (int nkb = 0; nkb < 4; ++nkb)
            bcur[nkb] = *(const f32x4*)&brow[ktn * 64 + nkb * 16 + lg * 4];
        __builtin_amdgcn_sched_barrier(0);

        // c5: P -> wave-private LDS; rescale acc
#pragma unroll
        for (int nkb = 0; nkb < 4; ++nkb) {
            __hip_bfloat16 pk[4];
#pragma unroll
            for (int j = 0; j < 4; ++j) pk[j] = __float2bfloat16(s[nkb][j]);
            *(short4*)&Pl[w][lr][nkb * 16 + lg * 4] = *(const short4*)pk;
        }
        float alr[4];
#pragma unroll
        for (int j = 0; j < 4; ++j) alr[j] = __shfl(al, lg * 4 + j);
#pragma unroll
        for (int db = 0; db < 4; ++db)
#pragma unroll
            for (int j = 0; j < 4; ++j) acc[db][j] *= alr[j];

        // c6: PV (consumes vf(kt); Pl reads fenced by compiler lgkmcnt)
        bf16x8 paf[2];
        paf[0] = *(const bf16x8*)&Pl[w][lr][lg * 8];
        paf[1] = *(const bf16x8*)&Pl[w][lr][32 + lg * 8];
        __builtin_amdgcn_s_setprio(1);
#pragma unroll
        for (int db = 0; db < 4; ++db)
#pragma unroll
            for (int mh = 0; mh < 2; ++mh)
                acc[db] = __builtin_amdgcn_mfma_f32_16x16x32_bf16(paf[mh], vf[db][mh],
                                                                  acc[db], 0, 0, 0);
        __builtin_amdgcn_s_setprio(0);
        __builtin_amdgcn_sched_barrier(0);

        // c7: issue V(kt+1)
#pragma unroll
        for (int db = 0; db < 4; ++db)
#pragma unroll
            for (int mh = 0; mh < 2; ++mh)
                vf[db][mh] = *(const bf16x8*)
                    &vb0[(db * 16) * (size_t)N_ + ktn * 64 + mh * 32];
        __builtin_amdgcn_sched_barrier(0);
    }

    // epilogue
    float linv[4];
#pragma unroll
    for (int j = 0; j < 4; ++j) linv[j] = 1.f / __shfl(l_, lg * 4 + j);
#pragma unroll
    for (int db = 0; db < 4; ++db)
#pragma unroll
        for (int j = 0; j < 4; ++j)
            ao[((size_t)b * N_ + orow_base + j) * C_ + h * 64 + db * 16 + lr] =
                __float2bfloat16(acc[db][j] * linv[j]);
}

// ---------------------------------------------------------------- launcher
extern "C" void kernel_launch(void* const* d_in, const int* in_sizes, int n_in,
                              void* d_out, int out_size, void* d_ws, size_t ws_size,
                              hipStream_t stream) {
    const float* x    = (const float*)d_in[0];
    const float* bias = (const float*)d_in[1];
    const int*   mask = (const int*)d_in[2];
    const float* Wq   = (const float*)d_in[3];
    const float* bq   = (const float*)d_in[4];
    const float* Wk   = (const float*)d_in[5];
    const float* bk   = (const float*)d_in[6];
    const float* Wv   = (const float*)d_in[7];
    const float* bv   = (const float*)d_in[8];
    const float* Wo   = (const float*)d_in[9];
    const float* bo   = (const float*)d_in[10];
    float* out = (float*)d_out;

    char* ws = (char*)d_ws;
    const size_t MB = 1u << 20;
    __hip_bfloat16* xb  = (__hip_bfloat16*)(ws + 0 * MB);   // 8 MB
    __hip_bfloat16* wqb = (__hip_bfloat16*)(ws + 8 * MB);   // 2 MB each
    __hip_bfloat16* wkb = (__hip_bfloat16*)(ws + 10 * MB);
    __hip_bfloat16* wvb = (__hip_bfloat16*)(ws + 12 * MB);
    __hip_bfloat16* wob = (__hip_bfloat16*)(ws + 14 * MB);
    __hip_bfloat16* qb  = (__hip_bfloat16*)(ws + 16 * MB);  // 8 MB
    __hip_bfloat16* kb  = (__hip_bfloat16*)(ws + 24 * MB);  // 8 MB
    __hip_bfloat16* vtb = (__hip_bfloat16*)(ws + 32 * MB);  // 8 MB
    __hip_bfloat16* aob = (__hip_bfloat16*)(ws + 40 * MB);  // 8 MB

    f2b_kernel<<<4096, 256, 0, stream>>>(x, xb, B_ * N_ * C_);
    f2b4_kernel<<<dim3(1024, 4), 256, 0, stream>>>(Wq, Wk, Wv, Wo, wqb, wkb, wvb, wob);

    gemm_qkv<<<dim3(24, 32), 256, 0, stream>>>(xb, wqb, wkb, wvb, bq, bk, bv, qb, kb, vtb);

    attn_kernel<<<1024, 256, 0, stream>>>(qb, kb, vtb, bias, mask, aob);

    gemm_out<<<dim3(8, 32), 256, 0, stream>>>(aob, wob, bo, out);
}